// Round 16
// baseline (124.515 us; speedup 1.0000x reference)
//
#include <hip/hip_runtime.h>

// ---------- small helpers ----------
typedef __attribute__((ext_vector_type(8))) short bf16x8;
typedef __attribute__((ext_vector_type(4))) float f32x4;
typedef __attribute__((ext_vector_type(8))) unsigned short u16x8;

typedef const __attribute__((address_space(1))) void* as1cv;
typedef __attribute__((address_space(3))) void* as3v;

__device__ __forceinline__ unsigned short f2bf(float f) {
    union { float f; unsigned u; } x; x.f = f;
    unsigned r = x.u + 0x7FFFu + ((x.u >> 16) & 1u);   // RNE
    return (unsigned short)(r >> 16);
}
__device__ __forceinline__ float bf2f(unsigned short u) {
    union { unsigned u; float f; } x; x.u = ((unsigned)u) << 16; return x.f;
}

// ---------- 1. prep: W transpose (0..511) + x cvt (512..2559) + totals zero (2560) ----------
__global__ __launch_bounds__(256) void k_prep(
    const float* __restrict__ x, unsigned short* __restrict__ x_bf, long n,
    const float* __restrict__ W1, unsigned short* __restrict__ W1t,
    const float* __restrict__ W2, unsigned short* __restrict__ W2t,
    float* __restrict__ totals)
{
    __shared__ float tile[64][65];
    const int bid = blockIdx.x;
    const int tid = threadIdx.x;
    if (bid < 512) {
        const float* W = (bid >= 256) ? W2 : W1;
        unsigned short* Wt = (bid >= 256) ? W2t : W1t;
        const int rem = bid & 255;
        const int r0 = (rem >> 4) * 64, c0 = (rem & 15) * 64;
        #pragma unroll
        for (int i = 0; i < 16; ++i) {
            int idx = tid + i * 256;
            int r = idx >> 6, c = idx & 63;
            tile[r][c] = W[(long)(r0 + r) * 1024 + (c0 + c)];
        }
        __syncthreads();
        #pragma unroll
        for (int i = 0; i < 16; ++i) {
            int idx = tid + i * 256;
            int r = idx >> 6, c = idx & 63;
            Wt[(long)(c0 + r) * 1024 + (r0 + c)] = f2bf(tile[c][r]);
        }
    } else if (bid < 2560) {
        long i = (long)(bid - 512) * 256 + tid;
        const long stride = 2048L * 256;
        const long n4 = n >> 2;
        for (long j = i; j < n4; j += stride) {
            float4 v = ((const float4*)x)[j];
            ushort4 o;
            o.x = f2bf(v.x); o.y = f2bf(v.y); o.z = f2bf(v.z); o.w = f2bf(v.w);
            ((ushort4*)x_bf)[j] = o;
        }
    } else {
        #pragma unroll
        for (int i = 0; i < 32; ++i)
            totals[tid + i * 256] = 0.f;
    }
}

// ---------- 2. GEMM 256x256, merged 4-phase/iter (2 phases per K=64 buffer) ----------
// Evolution of the proven R15 kernel: same 4 barriers/iter at the same hazard
// points, same vmcnt(4) retire-sets, same tail peel (VM0), same epilogue.
// Change: phase pairs merged -> 4 lgkmcnt(0) drains per iter instead of 8,
// 32-MFMA clusters instead of 16. Hazard ledger:
//   BAR_a (after M1): buf0 B-frag reads in regs before M2 stages buf0-B(kt2)
//   BAR_b (after M2+VM4): publish buf1 (A kt1 from M1, B kt1 from prev M4);
//                         buf0-A reads (drained in M2) before M3 stages buf0-A
//   BAR_c (after M3): buf1 B-frag reads in regs before M4 stages buf1-B(kt3)
//   BAR_d (after M4+VM4): publish buf0 (B kt2 from M2, A kt2 from M3)
template<int OUT_BF16, int DO_COLSUM>
__global__ __launch_bounds__(512, 2) void k_gemm256(
    const unsigned short* __restrict__ A,
    const unsigned short* __restrict__ Bt,
    const float* __restrict__ bias,
    void* __restrict__ C,
    float* __restrict__ totals,
    int M, int N, int K)
{
    __shared__ unsigned short lds[2][4][8192];
    const int tid  = threadIdx.x;
    const int lane = tid & 63;
    const int w    = tid >> 6;          // wave 0..7
    const int wm   = w >> 2;            // 0..1 (M half)
    const int wn   = w & 3;             // 0..3 (N quarter)

    const int nwg = gridDim.x;
    const int cpx = nwg >> 3;
    const int wg  = (blockIdx.x & 7) * cpx + (blockIdx.x >> 3);
    const int nblks = N >> 8;
    const int mblk = wg / nblks, nblk = wg % nblks;
    const long m0 = (long)mblk << 8, n0 = (long)nblk << 8;

    const int segRow  = lane >> 3;
    const long segColE = (long)(((lane & 7) ^ segRow) << 3);

    const int rr = lane & 15, cc = lane >> 4;
    const int smask = (rr & 7) << 4;
    const int colSwz0 = (((cc * 16) ^ smask) >> 1);
    const int colSwz1 = (((64 + cc * 16) ^ smask) >> 1);

    auto stage = [&](int buf, int slot, const unsigned short* src, long rowBase, int kt) {
        #pragma unroll
        for (int g = 0; g < 2; ++g) {
            const int s = w + g * 8;
            const unsigned short* gp = src + (rowBase + s * 8 + segRow) * (long)K
                                           + (long)kt * 64 + segColE;
            __builtin_amdgcn_global_load_lds((as1cv)gp,
                (as3v)(&lds[buf][slot][s * 512 + lane * 8]), 16, 0, 0);
        }
    };

    f32x4 acc[8][4];
    #pragma unroll
    for (int i = 0; i < 8; ++i)
        #pragma unroll
        for (int j = 0; j < 4; ++j)
            acc[i][j] = (f32x4){0.f, 0.f, 0.f, 0.f};

    bf16x8 bfrag[4][2];
    const int bRowBase = (wn & 1) * 64;
    const int NK = K >> 6;
    const int ITERS = K >> 7;

#define VM4   asm volatile("s_waitcnt vmcnt(4)" ::: "memory")
#define VM0   asm volatile("s_waitcnt vmcnt(0)" ::: "memory")
#define BAR   __builtin_amdgcn_s_barrier()
// merged phase: quadrants 2H and 2H+1 of buffer BUF (32 MFMA)
#define PH2(BUF, H, STAGES, VMW) do {                                                \
    bf16x8 a00, a01, a10, a11, a20, a21, a30, a31;                                   \
    { const unsigned short* Ah = &lds[BUF][wm][0];                                   \
      a00 = *(const bf16x8*)(Ah + ((2*(H))*32 + rr) * 64 + colSwz0);                 \
      a01 = *(const bf16x8*)(Ah + ((2*(H))*32 + rr) * 64 + colSwz1);                 \
      a10 = *(const bf16x8*)(Ah + ((2*(H))*32 + 16 + rr) * 64 + colSwz0);            \
      a11 = *(const bf16x8*)(Ah + ((2*(H))*32 + 16 + rr) * 64 + colSwz1);            \
      a20 = *(const bf16x8*)(Ah + ((2*(H)+1)*32 + rr) * 64 + colSwz0);               \
      a21 = *(const bf16x8*)(Ah + ((2*(H)+1)*32 + rr) * 64 + colSwz1);               \
      a30 = *(const bf16x8*)(Ah + ((2*(H)+1)*32 + 16 + rr) * 64 + colSwz0);          \
      a31 = *(const bf16x8*)(Ah + ((2*(H)+1)*32 + 16 + rr) * 64 + colSwz1); }        \
    if ((H) == 0) { const unsigned short* Bh = &lds[BUF][2 + (wn >> 1)][0];          \
      _Pragma("unroll")                                                              \
      for (int nj = 0; nj < 4; ++nj) {                                               \
        bfrag[nj][0] = *(const bf16x8*)(Bh + (bRowBase + nj*16 + rr) * 64 + colSwz0);\
        bfrag[nj][1] = *(const bf16x8*)(Bh + (bRowBase + nj*16 + rr) * 64 + colSwz1);\
      } }                                                                            \
    STAGES;                                                                          \
    VMW;                                                                             \
    asm volatile("s_waitcnt lgkmcnt(0)" ::: "memory");                               \
    __builtin_amdgcn_sched_barrier(0);                                               \
    __builtin_amdgcn_s_setprio(1);                                                   \
    _Pragma("unroll")                                                                \
    for (int nj = 0; nj < 4; ++nj) {                                                 \
      acc[4*(H)][nj]   = __builtin_amdgcn_mfma_f32_16x16x32_bf16(a00, bfrag[nj][0], acc[4*(H)][nj],   0,0,0); \
      acc[4*(H)][nj]   = __builtin_amdgcn_mfma_f32_16x16x32_bf16(a01, bfrag[nj][1], acc[4*(H)][nj],   0,0,0); \
      acc[4*(H)+1][nj] = __builtin_amdgcn_mfma_f32_16x16x32_bf16(a10, bfrag[nj][0], acc[4*(H)+1][nj], 0,0,0); \
      acc[4*(H)+1][nj] = __builtin_amdgcn_mfma_f32_16x16x32_bf16(a11, bfrag[nj][1], acc[4*(H)+1][nj], 0,0,0); \
      acc[4*(H)+2][nj] = __builtin_amdgcn_mfma_f32_16x16x32_bf16(a20, bfrag[nj][0], acc[4*(H)+2][nj], 0,0,0); \
      acc[4*(H)+2][nj] = __builtin_amdgcn_mfma_f32_16x16x32_bf16(a21, bfrag[nj][1], acc[4*(H)+2][nj], 0,0,0); \
      acc[4*(H)+3][nj] = __builtin_amdgcn_mfma_f32_16x16x32_bf16(a30, bfrag[nj][0], acc[4*(H)+3][nj], 0,0,0); \
      acc[4*(H)+3][nj] = __builtin_amdgcn_mfma_f32_16x16x32_bf16(a31, bfrag[nj][1], acc[4*(H)+3][nj], 0,0,0); \
    }                                                                                \
    __builtin_amdgcn_s_setprio(0);                                                   \
} while (0)

    // prologue (unchanged ledger): stage kt0 x4 + kt1-B x2; retire kt0; publish
    stage(0, 0, A,  m0,       0);
    stage(0, 1, A,  m0 + 128, 0);
    stage(0, 2, Bt, n0,       0);
    stage(0, 3, Bt, n0 + 128, 0);
    stage(1, 2, Bt, n0,       1);
    stage(1, 3, Bt, n0 + 128, 1);
    VM4;
    BAR;

    for (int it = 0; it < ITERS - 1; ++it) {
        const int kt1 = 2 * it + 1;
        const int kt2 = 2 * it + 2;
        const int kt3 = 2 * it + 3;

        PH2(0, 0, { stage(1, 0, A,  m0, kt1); stage(1, 1, A,  m0 + 128, kt1); }, );
        BAR;                                    // BAR_a
        PH2(0, 1, { stage(0, 2, Bt, n0, kt2); stage(0, 3, Bt, n0 + 128, kt2); }, VM4);
        BAR;                                    // BAR_b: publish buf1 (kt1)
        PH2(1, 0, { stage(0, 0, A,  m0, kt2); stage(0, 1, A,  m0 + 128, kt2); }, );
        BAR;                                    // BAR_c
        PH2(1, 1, { stage(1, 2, Bt, n0, kt3); stage(1, 3, Bt, n0 + 128, kt3); }, VM4);
        BAR;                                    // BAR_d: publish buf0 (kt2)
    }

    // peeled final iteration: buf0 = kt NK-2; stage only buf1-A (kt NK-1);
    // VM0 retires buf1-A (M1) + buf1-B (prev M4) exactly.
    {
        PH2(0, 0, { stage(1, 0, A, m0, NK - 1); stage(1, 1, A, m0 + 128, NK - 1); }, );
        PH2(0, 1, , VM0);
        BAR;                                    // publish buf1 (kt NK-1)
        PH2(1, 0, , );
        PH2(1, 1, , );
    }
#undef PH2
#undef BAR
#undef VM0
#undef VM4

    // epilogue — frozen order: mi-outer, nj-mid, jj-inner
    float cs[4] = {0.f, 0.f, 0.f, 0.f};
    #pragma unroll
    for (int mi = 0; mi < 8; ++mi) {
        const long rowb = m0 + wm * 128 + mi * 16 + cc * 4;
        #pragma unroll
        for (int nj = 0; nj < 4; ++nj) {
            const long col = n0 + wn * 64 + nj * 16 + rr;
            const float bv = bias[col];
            #pragma unroll
            for (int jj = 0; jj < 4; ++jj) {
                const float v = acc[mi][nj][jj] + bv;
                if (DO_COLSUM) cs[nj] += v;
                if (OUT_BF16) ((unsigned short*)C)[(rowb + jj) * N + col] = f2bf(v);
                else          ((float*)C)[(rowb + jj) * N + col] = v;
            }
        }
    }
    if (DO_COLSUM) {
        const int b = (int)(m0 >> 11);      // 2048 rows per batch
        #pragma unroll
        for (int nj = 0; nj < 4; ++nj) {
            float c0 = cs[nj];
            c0 += __shfl_xor(c0, 16, 64);
            c0 += __shfl_xor(c0, 32, 64);
            if (cc == 0)
                atomicAdd(totals + b * 1024 + n0 + wn * 64 + nj * 16 + rr, c0);
        }
    }
}

// ---------- 3. FSMN v4: burst-load window + taps in regs, 32 outputs/thread ----------
#define FS_ROWS 167   // 128 + 39
__global__ __launch_bounds__(256, 2) void k_fsmn(
    const unsigned short* __restrict__ p,   // (B*T, 1024) bf16
    const float* __restrict__ mw,           // (41, 1024) fp32
    const float* __restrict__ total,        // (B, 1024) fp32
    unsigned short* __restrict__ p2,        // (B*T, 1024) bf16
    int T)
{
    __shared__ unsigned short sp[FS_ROWS][64];   // [c][d], t = t0 + c - 39
    __shared__ float smw[41][64];
    const int b  = blockIdx.z;
    const int t0 = blockIdx.y * 128;
    const int d0 = blockIdx.x * 64;
    const int tid = threadIdx.x;

    for (int idx = tid; idx < 41 * 64; idx += 256) {
        int r = idx >> 6, c = idx & 63;
        smw[r][c] = mw[r * 1024 + d0 + c];
    }
    {
        const int row0 = tid >> 3;
        const int col8 = (tid & 7) * 8;
        #pragma unroll
        for (int i = 0; i < 6; ++i) {
            const int row = row0 + i * 32;
            if (row < FS_ROWS) {
                const int t = t0 + row - 39;
                u16x8 v = {0, 0, 0, 0, 0, 0, 0, 0};
                if (t >= 0)
                    v = *(const u16x8*)(p + ((long)b * T + t) * 1024 + d0 + col8);
                *(u16x8*)(&sp[row][col8]) = v;
            }
        }
    }
    __syncthreads();

    const int lane = tid & 63, wv = tid >> 6;
    const int d = d0 + lane;

    float m[40];
    #pragma unroll
    for (int l = 0; l < 40; ++l) m[l] = smw[l + 1][lane];
    const float m0v = smw[0][lane];
    const float tot = total[b * 1024 + d];

    #pragma unroll
    for (int pass = 0; pass < 2; ++pass) {
        const int obase = wv * 32 + pass * 16;
        float w[55];
        #pragma unroll
        for (int j = 0; j < 55; ++j) w[j] = bf2f(sp[obase + j][lane]);

        float acc[16];
        #pragma unroll
        for (int s = 0; s < 16; ++s) acc[s] = 0.f;
        #pragma unroll
        for (int lag = 0; lag < 40; ++lag) {
            const float mm = m[lag];
            #pragma unroll
            for (int s = 0; s < 16; ++s)
                acc[s] = fmaf(mm, w[s + 39 - lag], acc[s]);
        }

        float accw[16];
        {
            float S = 0.f;
            #pragma unroll
            for (int j = 0; j < 40; ++j) S += w[j];
            accw[0] = S;
            #pragma unroll
            for (int s = 1; s < 16; ++s) accw[s] = accw[s - 1] + w[s + 39] - w[s - 1];
        }

        unsigned short* ob = p2 + ((long)b * T + t0 + obase) * 1024 + d;
        #pragma unroll
        for (int s = 0; s < 16; ++s)
            ob[(long)s * 1024] = f2bf(acc[s] + m0v * (tot - accw[s]));
    }
}

// ---------- launch ----------
extern "C" void kernel_launch(void* const* d_in, const int* in_sizes, int n_in,
                              void* d_out, int out_size, void* d_ws, size_t ws_size,
                              hipStream_t stream) {
    const float* x  = (const float*)d_in[0];
    const float* W1 = (const float*)d_in[1];
    const float* b1 = (const float*)d_in[2];
    const float* W2 = (const float*)d_in[3];
    const float* b2 = (const float*)d_in[4];
    const float* mw = (const float*)d_in[5];
    float* out = (float*)d_out;

    const int B = 8, T = 2048;
    const long M = (long)B * T;          // 16384 rows
    const int N = 1024, K = 1024;

    char* ws = (char*)d_ws;
    unsigned short* x_bf   = (unsigned short*)(ws);
    unsigned short* W1t    = (unsigned short*)(ws + 33554432L);
    unsigned short* W2t    = (unsigned short*)(ws + 35651584L);
    unsigned short* p_bf   = (unsigned short*)(ws + 37748736L);
    float*          totals = (float*)(ws + 71303168L);
    unsigned short* p2_bf  = x_bf;

    k_prep<<<2561, 256, 0, stream>>>(x, x_bf, M * 1024, W1, W1t, W2, W2t, totals);

    k_gemm256<1, 1><<<dim3((int)((M / 256) * (N / 256))), 512, 0, stream>>>(
        x_bf, W1t, b1, (void*)p_bf, totals, (int)M, N, K);

    k_fsmn<<<dim3(1024 / 64, T / 128, B), 256, 0, stream>>>(p_bf, mw, totals, p2_bf, T);

    k_gemm256<0, 0><<<dim3((int)((M / 256) * (N / 256))), 512, 0, stream>>>(
        p2_bf, W2t, b2, (void*)out, nullptr, (int)M, N, K);
}

// Round 17
// 121.590 us; speedup vs baseline: 1.0241x; 1.0241x over previous
//
#include <hip/hip_runtime.h>

// ---------- small helpers ----------
typedef __attribute__((ext_vector_type(8))) short bf16x8;
typedef __attribute__((ext_vector_type(4))) float f32x4;
typedef __attribute__((ext_vector_type(8))) unsigned short u16x8;

typedef const __attribute__((address_space(1))) void* as1cv;
typedef __attribute__((address_space(3))) void* as3v;

__device__ __forceinline__ unsigned short f2bf(float f) {
    union { float f; unsigned u; } x; x.f = f;
    unsigned r = x.u + 0x7FFFu + ((x.u >> 16) & 1u);   // RNE
    return (unsigned short)(r >> 16);
}
__device__ __forceinline__ float bf2f(unsigned short u) {
    union { unsigned u; float f; } x; x.u = ((unsigned)u) << 16; return x.f;
}

// ---------- 1. prep: W transpose (0..511) + x cvt (512..2559) + totals zero (2560) ----------
__global__ __launch_bounds__(256) void k_prep(
    const float* __restrict__ x, unsigned short* __restrict__ x_bf, long n,
    const float* __restrict__ W1, unsigned short* __restrict__ W1t,
    const float* __restrict__ W2, unsigned short* __restrict__ W2t,
    float* __restrict__ totals)
{
    __shared__ float tile[64][65];
    const int bid = blockIdx.x;
    const int tid = threadIdx.x;
    if (bid < 512) {
        const float* W = (bid >= 256) ? W2 : W1;
        unsigned short* Wt = (bid >= 256) ? W2t : W1t;
        const int rem = bid & 255;
        const int r0 = (rem >> 4) * 64, c0 = (rem & 15) * 64;
        #pragma unroll
        for (int i = 0; i < 16; ++i) {
            int idx = tid + i * 256;
            int r = idx >> 6, c = idx & 63;
            tile[r][c] = W[(long)(r0 + r) * 1024 + (c0 + c)];
        }
        __syncthreads();
        #pragma unroll
        for (int i = 0; i < 16; ++i) {
            int idx = tid + i * 256;
            int r = idx >> 6, c = idx & 63;
            Wt[(long)(c0 + r) * 1024 + (r0 + c)] = f2bf(tile[c][r]);
        }
    } else if (bid < 2560) {
        long i = (long)(bid - 512) * 256 + tid;
        const long stride = 2048L * 256;
        const long n4 = n >> 2;
        for (long j = i; j < n4; j += stride) {
            float4 v = ((const float4*)x)[j];
            ushort4 o;
            o.x = f2bf(v.x); o.y = f2bf(v.y); o.z = f2bf(v.z); o.w = f2bf(v.w);
            ((ushort4*)x_bf)[j] = o;
        }
    } else {
        // zero totals (8 * 1024 floats)
        #pragma unroll
        for (int i = 0; i < 32; ++i)
            totals[tid + i * 256] = 0.f;
    }
}

// ---------- 2. GEMM 256x256 8-phase, 4-barriers-per-iter + peeled tail ----------
// Frozen: per-wave issue/wait order, vmcnt(4) ledger, barrier placement,
// epilogue store order (mi-outer/nj-mid/jj-inner), 16-MFMA phase granularity
// (R16 showed 32-MFMA clusters are neutral-to-worse). R6/R7/R9/R10/R13/R16.
template<int OUT_BF16, int DO_COLSUM>
__global__ __launch_bounds__(512, 2) void k_gemm256(
    const unsigned short* __restrict__ A,
    const unsigned short* __restrict__ Bt,
    const float* __restrict__ bias,
    void* __restrict__ C,
    float* __restrict__ totals,
    int M, int N, int K)
{
    __shared__ unsigned short lds[2][4][8192];
    const int tid  = threadIdx.x;
    const int lane = tid & 63;
    const int w    = tid >> 6;          // wave 0..7
    const int wm   = w >> 2;            // 0..1 (M half)
    const int wn   = w & 3;             // 0..3 (N quarter)

    const int nwg = gridDim.x;
    const int cpx = nwg >> 3;
    const int wg  = (blockIdx.x & 7) * cpx + (blockIdx.x >> 3);
    const int nblks = N >> 8;
    const int mblk = wg / nblks, nblk = wg % nblks;
    const long m0 = (long)mblk << 8, n0 = (long)nblk << 8;

    const int segRow  = lane >> 3;
    const long segColE = (long)(((lane & 7) ^ segRow) << 3);

    const int rr = lane & 15, cc = lane >> 4;
    const int smask = (rr & 7) << 4;
    const int colSwz0 = (((cc * 16) ^ smask) >> 1);
    const int colSwz1 = (((64 + cc * 16) ^ smask) >> 1);

    auto stage = [&](int buf, int slot, const unsigned short* src, long rowBase, int kt) {
        #pragma unroll
        for (int g = 0; g < 2; ++g) {
            const int s = w + g * 8;
            const unsigned short* gp = src + (rowBase + s * 8 + segRow) * (long)K
                                           + (long)kt * 64 + segColE;
            __builtin_amdgcn_global_load_lds((as1cv)gp,
                (as3v)(&lds[buf][slot][s * 512 + lane * 8]), 16, 0, 0);
        }
    };

    f32x4 acc[8][4];
    #pragma unroll
    for (int i = 0; i < 8; ++i)
        #pragma unroll
        for (int j = 0; j < 4; ++j)
            acc[i][j] = (f32x4){0.f, 0.f, 0.f, 0.f};

    bf16x8 bfrag[4][2];
    const int bRowBase = (wn & 1) * 64;
    const int NK = K >> 6;
    const int ITERS = K >> 7;

#define VM4   asm volatile("s_waitcnt vmcnt(4)" ::: "memory")
#define VM0   asm volatile("s_waitcnt vmcnt(0)" ::: "memory")
#define BAR   __builtin_amdgcn_s_barrier()
#define PH(BUF, Q, STAGES, VMW) do {                                                 \
    bf16x8 af0_0, af0_1, af1_0, af1_1;                                               \
    { const unsigned short* Ah = &lds[BUF][wm][0];                                   \
      af0_0 = *(const bf16x8*)(Ah + ((Q)*32 + rr) * 64 + colSwz0);                   \
      af0_1 = *(const bf16x8*)(Ah + ((Q)*32 + rr) * 64 + colSwz1);                   \
      af1_0 = *(const bf16x8*)(Ah + ((Q)*32 + 16 + rr) * 64 + colSwz0);              \
      af1_1 = *(const bf16x8*)(Ah + ((Q)*32 + 16 + rr) * 64 + colSwz1); }            \
    if ((Q) == 0) { const unsigned short* Bh = &lds[BUF][2 + (wn >> 1)][0];          \
      _Pragma("unroll")                                                              \
      for (int nj = 0; nj < 4; ++nj) {                                               \
        bfrag[nj][0] = *(const bf16x8*)(Bh + (bRowBase + nj*16 + rr) * 64 + colSwz0);\
        bfrag[nj][1] = *(const bf16x8*)(Bh + (bRowBase + nj*16 + rr) * 64 + colSwz1);\
      } }                                                                            \
    STAGES;                                                                          \
    VMW;                                                                             \
    asm volatile("s_waitcnt lgkmcnt(0)" ::: "memory");                               \
    __builtin_amdgcn_sched_barrier(0);                                               \
    __builtin_amdgcn_s_setprio(1);                                                   \
    _Pragma("unroll")                                                                \
    for (int nj = 0; nj < 4; ++nj) {                                                 \
      acc[2*(Q)][nj]   = __builtin_amdgcn_mfma_f32_16x16x32_bf16(af0_0, bfrag[nj][0], acc[2*(Q)][nj],   0,0,0); \
      acc[2*(Q)][nj]   = __builtin_amdgcn_mfma_f32_16x16x32_bf16(af0_1, bfrag[nj][1], acc[2*(Q)][nj],   0,0,0); \
      acc[2*(Q)+1][nj] = __builtin_amdgcn_mfma_f32_16x16x32_bf16(af1_0, bfrag[nj][0], acc[2*(Q)+1][nj], 0,0,0); \
      acc[2*(Q)+1][nj] = __builtin_amdgcn_mfma_f32_16x16x32_bf16(af1_1, bfrag[nj][1], acc[2*(Q)+1][nj], 0,0,0); \
    }                                                                                \
    __builtin_amdgcn_s_setprio(0);                                                   \
} while (0)

    // prologue: stage kt0 x4 + kt1-B x2; retire kt0; publish
    stage(0, 0, A,  m0,       0);
    stage(0, 1, A,  m0 + 128, 0);
    stage(0, 2, Bt, n0,       0);
    stage(0, 3, Bt, n0 + 128, 0);
    stage(1, 2, Bt, n0,       1);
    stage(1, 3, Bt, n0 + 128, 1);
    VM4;
    BAR;

    for (int it = 0; it < ITERS - 1; ++it) {
        const int kt1 = 2 * it + 1;
        const int kt2 = 2 * it + 2;
        const int kt3 = 2 * it + 3;

        PH(0, 0, stage(1, 0, A,  m0,       kt1), );
        PH(0, 1, stage(1, 1, A,  m0 + 128, kt1), );
        BAR;                                    // P1 B-reads done before P3 B-stage
        PH(0, 2, { stage(0, 2, Bt, n0, kt2); stage(0, 3, Bt, n0 + 128, kt2); }, );
        PH(0, 3, , VM4);
        BAR;                                    // publish buf1 (kt1 A + kt1 B)
        PH(1, 0, stage(0, 0, A,  m0,       kt2), );
        PH(1, 1, stage(0, 1, A,  m0 + 128, kt2), );
        BAR;                                    // P5 B-reads done before P7 B-stage
        PH(1, 2, { stage(1, 2, Bt, n0, kt3); stage(1, 3, Bt, n0 + 128, kt3); }, );
        PH(1, 3, , VM4);
        BAR;                                    // publish buf0 (kt2 A + kt2 B)
    }

    // peeled final iteration: buf0 holds kt (NK-2); stage only buf1-A (kt NK-1).
    // P4 waits vmcnt(0): retires buf1-A (P1/P2 here) + buf1-B (prev P7) exactly.
    {
        PH(0, 0, stage(1, 0, A,  m0,       NK - 1), );
        PH(0, 1, stage(1, 1, A,  m0 + 128, NK - 1), );
        PH(0, 2, , );
        PH(0, 3, , VM0);
        BAR;                                    // publish buf1 (kt NK-1)
        PH(1, 0, , );
        PH(1, 1, , );
        PH(1, 2, , );
        PH(1, 3, , );
    }
#undef PH
#undef BAR
#undef VM0
#undef VM4

    // epilogue — frozen order: mi-outer, nj-mid, jj-inner
    float cs[4] = {0.f, 0.f, 0.f, 0.f};
    #pragma unroll
    for (int mi = 0; mi < 8; ++mi) {
        const long rowb = m0 + wm * 128 + mi * 16 + cc * 4;
        #pragma unroll
        for (int nj = 0; nj < 4; ++nj) {
            const long col = n0 + wn * 64 + nj * 16 + rr;
            const float bv = bias[col];
            #pragma unroll
            for (int jj = 0; jj < 4; ++jj) {
                const float v = acc[mi][nj][jj] + bv;
                if (DO_COLSUM) cs[nj] += v;
                if (OUT_BF16) ((unsigned short*)C)[(rowb + jj) * N + col] = f2bf(v);
                else          ((float*)C)[(rowb + jj) * N + col] = v;
            }
        }
    }
    if (DO_COLSUM) {
        const int b = (int)(m0 >> 11);      // 2048 rows per batch
        #pragma unroll
        for (int nj = 0; nj < 4; ++nj) {
            float c0 = cs[nj];
            c0 += __shfl_xor(c0, 16, 64);
            c0 += __shfl_xor(c0, 32, 64);
            if (cc == 0)
                atomicAdd(totals + b * 1024 + n0 + wn * 64 + nj * 16 + rr, c0);
        }
    }
}

// ---------- 3. FSMN v4: burst-load window + taps in regs, 32 outputs/thread ----------
#define FS_ROWS 167   // 128 + 39
__global__ __launch_bounds__(256, 2) void k_fsmn(
    const unsigned short* __restrict__ p,   // (B*T, 1024) bf16
    const float* __restrict__ mw,           // (41, 1024) fp32
    const float* __restrict__ total,        // (B, 1024) fp32
    unsigned short* __restrict__ p2,        // (B*T, 1024) bf16
    int T)
{
    __shared__ unsigned short sp[FS_ROWS][64];   // [c][d], t = t0 + c - 39
    __shared__ float smw[41][64];
    const int b  = blockIdx.z;
    const int t0 = blockIdx.y * 128;
    const int d0 = blockIdx.x * 64;
    const int tid = threadIdx.x;

    for (int idx = tid; idx < 41 * 64; idx += 256) {
        int r = idx >> 6, c = idx & 63;
        smw[r][c] = mw[r * 1024 + d0 + c];
    }
    {
        const int row0 = tid >> 3;
        const int col8 = (tid & 7) * 8;
        #pragma unroll
        for (int i = 0; i < 6; ++i) {
            const int row = row0 + i * 32;
            if (row < FS_ROWS) {
                const int t = t0 + row - 39;
                u16x8 v = {0, 0, 0, 0, 0, 0, 0, 0};
                if (t >= 0)
                    v = *(const u16x8*)(p + ((long)b * T + t) * 1024 + d0 + col8);
                *(u16x8*)(&sp[row][col8]) = v;
            }
        }
    }
    __syncthreads();

    const int lane = tid & 63, wv = tid >> 6;
    const int d = d0 + lane;

    float m[40];
    #pragma unroll
    for (int l = 0; l < 40; ++l) m[l] = smw[l + 1][lane];
    const float m0v = smw[0][lane];
    const float tot = total[b * 1024 + d];

    #pragma unroll
    for (int pass = 0; pass < 2; ++pass) {
        const int obase = wv * 32 + pass * 16;
        float w[55];
        #pragma unroll
        for (int j = 0; j < 55; ++j) w[j] = bf2f(sp[obase + j][lane]);

        float acc[16];
        #pragma unroll
        for (int s = 0; s < 16; ++s) acc[s] = 0.f;
        #pragma unroll
        for (int lag = 0; lag < 40; ++lag) {
            const float mm = m[lag];
            #pragma unroll
            for (int s = 0; s < 16; ++s)
                acc[s] = fmaf(mm, w[s + 39 - lag], acc[s]);
        }

        float accw[16];
        {
            float S = 0.f;
            #pragma unroll
            for (int j = 0; j < 40; ++j) S += w[j];
            accw[0] = S;
            #pragma unroll
            for (int s = 1; s < 16; ++s) accw[s] = accw[s - 1] + w[s + 39] - w[s - 1];
        }

        unsigned short* ob = p2 + ((long)b * T + t0 + obase) * 1024 + d;
        #pragma unroll
        for (int s = 0; s < 16; ++s)
            ob[(long)s * 1024] = f2bf(acc[s] + m0v * (tot - accw[s]));
    }
}

// ---------- launch ----------
extern "C" void kernel_launch(void* const* d_in, const int* in_sizes, int n_in,
                              void* d_out, int out_size, void* d_ws, size_t ws_size,
                              hipStream_t stream) {
    const float* x  = (const float*)d_in[0];
    const float* W1 = (const float*)d_in[1];
    const float* b1 = (const float*)d_in[2];
    const float* W2 = (const float*)d_in[3];
    const float* b2 = (const float*)d_in[4];
    const float* mw = (const float*)d_in[5];
    float* out = (float*)d_out;

    const int B = 8, T = 2048;
    const long M = (long)B * T;          // 16384 rows
    const int N = 1024, K = 1024;

    char* ws = (char*)d_ws;
    unsigned short* x_bf   = (unsigned short*)(ws);
    unsigned short* W1t    = (unsigned short*)(ws + 33554432L);
    unsigned short* W2t    = (unsigned short*)(ws + 35651584L);
    unsigned short* p_bf   = (unsigned short*)(ws + 37748736L);
    float*          totals = (float*)(ws + 71303168L);
    unsigned short* p2_bf  = x_bf;

    k_prep<<<2561, 256, 0, stream>>>(x, x_bf, M * 1024, W1, W1t, W2, W2t, totals);

    k_gemm256<1, 1><<<dim3((int)((M / 256) * (N / 256))), 512, 0, stream>>>(
        x_bf, W1t, b1, (void*)p_bf, totals, (int)M, N, K);

    k_fsmn<<<dim3(1024 / 64, T / 128, B), 256, 0, stream>>>(p_bf, mw, totals, p2_bf, T);

    k_gemm256<0, 0><<<dim3((int)((M / 256) * (N / 256))), 512, 0, stream>>>(
        p2_bf, W2t, b2, (void*)out, nullptr, (int)M, N, K);
}